// Round 3
// baseline (1007.196 us; speedup 1.0000x reference)
//
#include <hip/hip_runtime.h>

// x: (1024, 28, 64, 28) f32   [l, k, i, j]
// W: (128, 3, 32, 3)    f32   [co, kh, u, kw]
// out: (1024, 128, 28, 28) f32
//
// out[l,co,p,o] = sum_{kw} sum_{r=(kh,u)} W[co,kh,u,kw] * T6[l,r,p,o+kw-1]
// T6[l,(kh,u),p,v] = V(h=(p+27)%28,c=1) + V(h=p,c=0)
//   V(h,c): hh=h+kh-1; if hh in [0,28): q=8*hh+4c+u; X[l, q%28, 2*hh+c+q/28, v]
//
// v4: NL=8 l's per block, LDS double-buffer, T14 split (issue gathers early,
// ds_write after GEMM), 1 barrier per l. Zero-init + builder addressing hoisted.

typedef _Float16 f16x8 __attribute__((ext_vector_type(8)));
typedef float    f32x4 __attribute__((ext_vector_type(4)));

#define PG  4      // p's per block
#define PVN 34     // pv rows (pv = o + kw reaches 33)
#define RP  104    // r-stride in halves (96 padded; 208B rows -> 2-way banks, free)
#define NL  8      // l's per block
#define TILE_HALVES (PG * PVN * RP)   // 14144

// ---- W prep: W[co][kh][u][kw] f32 -> Ah[(kw*128+co)*96 + r] f16, r = kh*32+u
__global__ void w_prep_kernel(const float* __restrict__ W, _Float16* __restrict__ Ah) {
    int id = blockIdx.x * 256 + threadIdx.x;   // 0..36863
    if (id >= 3 * 128 * 96) return;
    int r  = id % 96;
    int t  = id / 96;          // kw*128 + co
    int co = t & 127;
    int kw = t >> 7;
    Ah[id] = (_Float16)W[co * 288 + (r >> 5) * 96 + (r & 31) * 3 + kw];
}

__global__ __launch_bounds__(256, 2) void mfma_shiftconv_kernel(
        const float* __restrict__ x,
        const _Float16* __restrict__ Ah,
        float* __restrict__ out) {
    __shared__ __align__(16) _Float16 T6L[2][TILE_HALVES];   // 56576 B

    const int p0  = blockIdx.x * PG;            // 0,4,..,24
    const int l0  = blockIdx.y * NL;            // 0,8,..,1016
    const int tid = threadIdx.x;                // 0..255

    const int lane = tid & 63;
    const int wid  = tid >> 6;
    const int wm   = wid >> 1;       // co block of 64
    const int wn   = wid & 1;        // column block of 64
    const int ln   = lane & 15;
    const int kb   = lane >> 4;

    // ---- hoisted builder addressing: 3 half-row tasks per thread ----
    // task = tid + 256*t3 in [0,768): row = task>>1 (p_loc*96 + r), half = task&1
    int  offs0[3], offs1[3], wraddr[3];
    bool has0[3], has1[3];
    #pragma unroll
    for (int t3 = 0; t3 < 3; ++t3) {
        int task  = tid + 256 * t3;
        int row   = task >> 1;
        int half  = task & 1;
        int p_loc = row / 96;
        int r     = row % 96;
        int kh    = r >> 5;
        int u     = r & 31;
        int v0    = 14 * half;
        int p_abs = p0 + p_loc;
        int h1    = (p_abs + 27) % 28;

        int hh0 = p_abs + kh - 1;
        has0[t3] = (hh0 >= 0 && hh0 < 28);
        offs0[t3] = 0;
        if (has0[t3]) {
            int q = 8 * hh0 + u;                       // < 248
            offs0[t3] = ((q % 28) * 64 + 2 * hh0 + (q / 28)) * 28 + v0;
        }
        int hh1 = h1 + kh - 1;
        has1[t3] = (hh1 >= 0 && hh1 < 28);
        offs1[t3] = 0;
        if (has1[t3]) {
            int q = 8 * hh1 + 4 + u;                   // < 252
            offs1[t3] = ((q % 28) * 64 + 2 * hh1 + 1 + (q / 28)) * 28 + v0;
        }
        wraddr[t3] = (p_loc * PVN + 1 + v0) * RP + r;  // pv = 1 + v
    }

    // ---- zero both buffers once (covers pad rows pv=0, pv>=29, r-pad) ----
    {
        f32x4 z = {0.f, 0.f, 0.f, 0.f};
        f32x4* T4 = (f32x4*)&T6L[0][0];
        for (int i = tid; i < (2 * TILE_HALVES) / 8; i += 256) T4[i] = z;
    }
    __syncthreads();

    const size_t XSTR = 28 * 64 * 28;
    float2 sa[3][7], sb[3][7];       // staged gathers (84 f32)

    // ---- prologue: build l0 into buffer 0 ----
    {
        const float* xl = x + (size_t)l0 * XSTR;
        #pragma unroll
        for (int t3 = 0; t3 < 3; ++t3) {
            #pragma unroll
            for (int k = 0; k < 7; ++k) {
                float2 a = {0.f, 0.f}, b = {0.f, 0.f};
                if (has0[t3]) a = *(const float2*)(xl + offs0[t3] + 2 * k);
                if (has1[t3]) b = *(const float2*)(xl + offs1[t3] + 2 * k);
                sa[t3][k] = a; sb[t3][k] = b;
            }
        }
        #pragma unroll
        for (int t3 = 0; t3 < 3; ++t3) {
            _Float16* w = &T6L[0][wraddr[t3]];
            #pragma unroll
            for (int k = 0; k < 7; ++k) {
                w[(2 * k + 0) * RP] = (_Float16)(sa[t3][k].x + sb[t3][k].x);
                w[(2 * k + 1) * RP] = (_Float16)(sa[t3][k].y + sb[t3][k].y);
            }
        }
    }
    __syncthreads();

    int cur = 0;
    for (int t = 0; t < NL; ++t) {
        const int  l    = l0 + t;
        const bool more = (t + 1 < NL);

        // ---- (1) issue next-l gathers into regs (latency hides under GEMM) ----
        if (more) {
            const float* xl = x + (size_t)(l + 1) * XSTR;
            #pragma unroll
            for (int t3 = 0; t3 < 3; ++t3) {
                #pragma unroll
                for (int k = 0; k < 7; ++k) {
                    float2 a = {0.f, 0.f}, b = {0.f, 0.f};
                    if (has0[t3]) a = *(const float2*)(xl + offs0[t3] + 2 * k);
                    if (has1[t3]) b = *(const float2*)(xl + offs1[t3] + 2 * k);
                    sa[t3][k] = a; sb[t3][k] = b;
                }
            }
        }

        // ---- (2) GEMM from buffer cur ----
        f32x4 acc[4][4];
        {
            f32x4 zz = {0.f, 0.f, 0.f, 0.f};
            #pragma unroll
            for (int a2 = 0; a2 < 4; ++a2)
                #pragma unroll
                for (int b2 = 0; b2 < 4; ++b2) acc[a2][b2] = zz;
        }
        const _Float16* Tc = &T6L[cur][0];
        #pragma unroll
        for (int kw = 0; kw < 3; ++kw) {
            #pragma unroll
            for (int kf = 0; kf < 3; ++kf) {
                const int rr = 32 * kf + 8 * kb;
                f16x8 afr[4];
                #pragma unroll
                for (int mf = 0; mf < 4; ++mf) {
                    int co = 64 * wm + 16 * mf + ln;
                    afr[mf] = *(const f16x8*)(Ah + ((kw * 128 + co) * 96 + rr));
                }
                #pragma unroll
                for (int nfl = 0; nfl < 4; ++nfl) {
                    int nf = 4 * wn + nfl;
                    int pv = (nf & 1) * 16 + ln + kw;
                    f16x8 bfr = *(const f16x8*)&Tc[((nf >> 1) * PVN + pv) * RP + rr];
                    #pragma unroll
                    for (int mf = 0; mf < 4; ++mf)
                        acc[mf][nfl] = __builtin_amdgcn_mfma_f32_16x16x32_f16(
                            afr[mf], bfr, acc[mf][nfl], 0, 0, 0);
                }
            }
        }

        // ---- (3) store l ----
        #pragma unroll
        for (int nfl = 0; nfl < 4; ++nfl) {
            int nf = 4 * wn + nfl;
            int o  = (nf & 1) * 16 + ln;
            if (o < 28) {
                int p_abs = p0 + (nf >> 1);
                #pragma unroll
                for (int mf = 0; mf < 4; ++mf) {
                    int co = 64 * wm + 16 * mf + 4 * kb;
                    float* op = out + (((size_t)l * 128 + co) * 28 + p_abs) * 28 + o;
                    #pragma unroll
                    for (int q = 0; q < 4; ++q) op[(size_t)q * 784] = acc[mf][nfl][q];
                }
            }
        }

        // ---- (4) write staged tile into buffer cur^1, one barrier per l ----
        if (more) {
            _Float16* Tn = &T6L[cur ^ 1][0];
            #pragma unroll
            for (int t3 = 0; t3 < 3; ++t3) {
                _Float16* w = &Tn[wraddr[t3]];
                #pragma unroll
                for (int k = 0; k < 7; ++k) {
                    w[(2 * k + 0) * RP] = (_Float16)(sa[t3][k].x + sb[t3][k].x);
                    w[(2 * k + 1) * RP] = (_Float16)(sa[t3][k].y + sb[t3][k].y);
                }
            }
            __syncthreads();
        }
        cur ^= 1;
    }
}

// ---- fallback (ws too small): known-good f32 kernel, direct W reads ----
__global__ void fallback_shiftconv_kernel(
        const float* __restrict__ x,
        const float* __restrict__ W,
        float* __restrict__ out) {
    __shared__ float T6F[3 * 32 * 32];

    const int p = blockIdx.x;
    const int l = blockIdx.y;
    const int tid = threadIdx.x;   // 0..127

    const float* __restrict__ xl = x + (size_t)l * (28 * 64 * 28);
    const int h1 = (p + 27) % 28;

    for (int e = tid; e < 3072; e += 128) {
        int kh = e >> 10;
        int u  = (e >> 5) & 31;
        int pv = e & 31;
        int v  = pv - 1;
        float val = 0.f;
        if (v >= 0 && v < 28) {
            int hh0 = p + kh - 1;
            if (hh0 >= 0 && hh0 < 28) {
                int q  = 8 * hh0 + u;
                val += xl[((q % 28) * 64 + 2 * hh0 + (q / 28)) * 28 + v];
            }
            int hh1 = h1 + kh - 1;
            if (hh1 >= 0 && hh1 < 28) {
                int q  = 8 * hh1 + 4 + u;
                val += xl[((q % 28) * 64 + 2 * hh1 + 1 + (q / 28)) * 28 + v];
            }
        }
        T6F[e] = val;
    }
    __syncthreads();

    const int g  = tid & 31;
    const int hq = tid >> 5;
    const int ob = 7 * hq;

    float acc[4][7];
    #pragma unroll
    for (int m = 0; m < 4; ++m)
        #pragma unroll
        for (int d = 0; d < 7; ++d) acc[m][d] = 0.f;

    for (int kh = 0; kh < 3; ++kh) {
        for (int u = 0; u < 32; ++u) {
            const float* tl = &T6F[(kh * 32 + u) * 32 + ob];
            float tv[9];
            #pragma unroll
            for (int t2 = 0; t2 < 9; ++t2) tv[t2] = tl[t2];

            #pragma unroll
            for (int kw = 0; kw < 3; ++kw) {
                const int off = kh * 96 + u * 3 + kw;
                float w0 = W[(4 * g + 0) * 288 + off];
                float w1 = W[(4 * g + 1) * 288 + off];
                float w2 = W[(4 * g + 2) * 288 + off];
                float w3 = W[(4 * g + 3) * 288 + off];
                #pragma unroll
                for (int d = 0; d < 7; ++d) {
                    const float t = tv[d + kw];
                    acc[0][d] += w0 * t;
                    acc[1][d] += w1 * t;
                    acc[2][d] += w2 * t;
                    acc[3][d] += w3 * t;
                }
            }
        }
    }

    const size_t base = (((size_t)l * 128 + 4 * g) * 28 + p) * 28 + ob;
    #pragma unroll
    for (int m = 0; m < 4; ++m)
        #pragma unroll
        for (int d = 0; d < 7; ++d)
            out[base + (size_t)m * 784 + d] = acc[m][d];
}

extern "C" void kernel_launch(void* const* d_in, const int* in_sizes, int n_in,
                              void* d_out, int out_size, void* d_ws, size_t ws_size,
                              hipStream_t stream) {
    (void)in_sizes; (void)n_in; (void)out_size;
    const float* x = (const float*)d_in[0];
    const float* W = (const float*)d_in[1];
    float* out = (float*)d_out;

    if (ws_size >= 36864 * sizeof(_Float16)) {
        _Float16* Ah = (_Float16*)d_ws;
        w_prep_kernel<<<144, 256, 0, stream>>>(W, Ah);
        mfma_shiftconv_kernel<<<dim3(7, 128), 256, 0, stream>>>(x, Ah, out);
    } else {
        fallback_shiftconv_kernel<<<dim3(28, 1024), 128, 0, stream>>>(x, W, out);
    }
}